// Round 10
// baseline (17.176 us; speedup 1.0000x reference)
//
#include <hip/hip_runtime.h>
#include <math.h>

// feat: (N=4, C3=147, H=64, W=64) fp32 ; out: (4, 3, 256, 256) fp32
// Exact structure (proved in fp32, verified R5-R9 passing, absmax 0.0625):
//  - interior j-group q (lane jg=q>=1): iw- = q-1, iw+ = q for all 4 j's;
//    lane 0 (merged {0,1,254,255}): pair0 -> col 0 both, pair1 -> col 63 both.
//    Same structure on the i axis.
//  - rel_plus = rel_minus - 2 (interior) / rel_minus (boundary) exactly ->
//    embed(rel-2) = sign-flip of embed(rel) on components {1,2,5,6}.
// R10 change vs R8: pairwise column ownership. Lanes 2u,2u+1 load float2
// spanning cols (2u,2u+1); even lanes take channels 0..27, odd 28..48
// (offset 28 = 0 mod 7 keeps bucket t%7 and coef index STATIC for both
// parities). One shfl_xor(1) pass merges the two partial colvecs.
// Halves VMEM instructions and addressing VALU vs R8.

#define FH 64
#define FW 64
#define FHW 4096          // FH*FW
#define NC3 147
#define OHW 256

__device__ __forceinline__ void embed7(float r, float e[7]) {
    const float F1  = 1.5707963705062866f;  // float32(0.5*pi)
    const float SQ2 = 1.4142135381698608f;  // float32(sqrt(2))
    float a = r * F1;
    float s1 = __sinf(a), c1 = __cosf(a);
    float s2 = 2.0f * s1 * c1, c2 = c1 * c1 - s1 * s1;
    float s3 = s2 * c1 + c2 * s1, c3 = c2 * c1 - s2 * s1;
    e[0] = 1.0f;
    e[1] = SQ2 * c1; e[2] = SQ2 * s1;
    e[3] = SQ2 * c2; e[4] = SQ2 * s2;
    e[5] = SQ2 * c3; e[6] = SQ2 * s3;
}

// block = (k, ib, n); wave = i-member m; lane = j-group jg.
__global__ __launch_bounds__(256, 3) void ope_render_kernel(
    const float* __restrict__ feat,
    const int* __restrict__ pflip1,
    const int* __restrict__ pflip3,
    float* __restrict__ out)
{
    const int tid = threadIdx.x;
    const int k   = blockIdx.x;   // 0..2
    const int ib  = blockIdx.y;   // 0..63 (ib==0 merged {0,1,254,255})
    const int n   = blockIdx.z;   // 0..3
    const int flip1 = pflip1[0];
    const int flip3 = pflip3[0];

    const bool boundary = (ib == 0);
    const int rA = boundary ? 0  : (ib - 1);
    const int rB = boundary ? 63 : ib;

    const int m  = tid >> 6;      // wave id = i-member
    const int jg = tid & 63;      // lane = j-group (own column)
    const int par  = jg & 1;      // parity within column pair
    const int colp = jg & ~1;     // pair base column
    const bool fx = (flip1 == 2) || (flip1 == 4);
    const bool fy = (flip1 == 1) || (flip1 == 4);
    const bool o  = (jg == 0);
    const float sgx = (flip3 == 2 || flip3 == 4) ? -1.0f : 1.0f;
    const float sgy = (flip3 == 1 || flip3 == 4) ? -1.0f : 1.0f;

    // x-axis: static rows; both corners' rel from one value
    const int i_e = boundary ? ((m < 2) ? m : 252 + m) : (4 * ib - 2 + m);
    const float cx = -1.0f + (2.0f * (float)i_e + 1.0f) * (1.0f / 256.0f);
    const int row0 = boundary ? ((m >> 1) ? rB : rA) : rA;   // minus-corner row
    const float qh0 = -1.0f + (2.0f * (float)row0 + 1.0f) * (1.0f / 64.0f);
    const float rel0_0 = (cx - qh0) * 64.0f;                  // exact
    const float rel0_1 = boundary ? rel0_0 : (rel0_0 - 2.0f); // exact

    float ex0[7], ex1[7];
    embed7(sgx * rel0_0, ex0);
    {   // embed(r -/+ 2) = sign-flip on {1,2,5,6}; boundary: identical
        const float xm = boundary ? 1.0f : -1.0f;
        ex1[0] = 1.0f;
        ex1[1] = xm * ex0[1]; ex1[2] = xm * ex0[2];
        ex1[3] = ex0[3];      ex1[4] = ex0[4];
        ex1[5] = xm * ex0[5]; ex1[6] = xm * ex0[6];
    }

    // parity-blended coefficient tables: lane channel c = 28*par + t,
    // coef = ex[c/7] = (par ? ex[4 + t/7] : ex[t/7]); odd t>20 is phantom (0)
    float ex0P[4], ex1P[4];
    #pragma unroll
    for (int i = 0; i < 4; ++i) {
        ex0P[i] = par ? ((i < 3) ? ex0[i + 4] : 0.0f) : ex0[i];
        ex1P[i] = par ? ((i < 3) ? ex1[i + 4] : 0.0f) : ex1[i];
    }

    // ---- direct-global float2 streamed contraction (no LDS, no barrier) ----
    // lane reads cols (colp, colp+1): each load = 512B coalesced per wave.
    const size_t chb = (size_t)n * NC3 + k * 49 + 28 * par;
    const float* __restrict__ p0 =
        feat + (chb * FH + row0) * FW + colp;
    float2 acc0[7], acc1[7];
    #pragma unroll
    for (int b = 0; b < 7; ++b) {
        acc0[b] = make_float2(0.0f, 0.0f);
        acc1[b] = make_float2(0.0f, 0.0f);
    }
    if (!boundary) {
        const float* __restrict__ p1 = p0 + (rB - rA) * FW;   // row rB
        #pragma unroll
        for (int t = 0; t < 28; ++t) {
            const int ce = (t > 20) ? (par ? 20 : t) : t;   // clamp phantoms
            float2 v0 = *(const float2*)(p0 + (size_t)ce * FHW);
            float2 v1 = *(const float2*)(p1 + (size_t)ce * FHW);
            const float e0 = ex0P[t / 7];
            const float e1 = ex1P[t / 7];
            acc0[t % 7].x = fmaf(e0, v0.x, acc0[t % 7].x);
            acc0[t % 7].y = fmaf(e0, v0.y, acc0[t % 7].y);
            acc1[t % 7].x = fmaf(e1, v1.x, acc1[t % 7].x);
            acc1[t % 7].y = fmaf(e1, v1.y, acc1[t % 7].y);
        }
    } else {
        #pragma unroll
        for (int t = 0; t < 28; ++t) {
            const int ce = (t > 20) ? (par ? 20 : t) : t;
            float2 v0 = *(const float2*)(p0 + (size_t)ce * FHW);
            const float e0 = ex0P[t / 7];
            acc0[t % 7].x = fmaf(e0, v0.x, acc0[t % 7].x);
            acc0[t % 7].y = fmaf(e0, v0.y, acc0[t % 7].y);
        }
    }

    // ---- merge parity partials: one shfl_xor(1) pass ----
    // lane sends the partner-column component, keeps its own-column component.
    float cv0[7], cv1[7];
    #pragma unroll
    for (int b = 0; b < 7; ++b) {
        float s0 = par ? acc0[b].x : acc0[b].y;   // partner's col
        float o0 = par ? acc0[b].y : acc0[b].x;   // own col
        cv0[b] = o0 + __shfl_xor(s0, 1, 64);
        if (!boundary) {
            float s1 = par ? acc1[b].x : acc1[b].y;
            float o1 = par ? acc1[b].y : acc1[b].x;
            cv1[b] = o1 + __shfl_xor(s1, 1, 64);
        }
    }
    if (boundary) {
        #pragma unroll
        for (int b = 0; b < 7; ++b) cv1[b] = cv0[b];   // same row, ex1==ex0
    }

    // ---- neighbor column via intra-wave shuffle (lane jg-1; lane0 <- 63) ----
    const int srcl = (jg + 63) & 63;
    float qv0[7], qv1[7];
    #pragma unroll
    for (int b = 0; b < 7; ++b) {
        qv0[b] = __shfl(cv0[b], srcl, 64);
        qv1[b] = __shfl(cv1[b], srcl, 64);
    }

    // ---- per-pair inline y-math + dots (verified R5-R9) ----
    const float tm = o ? 0.0f : -2.0f;   // rel1_plus = rel1_minus + tm
    const float ym = o ? 1.0f : -1.0f;   // ey1 sign multiplier
    float acc_0, acc_1, acc_2, acc_3;
    #pragma unroll
    for (int p = 0; p < 2; ++p) {
        const int jb = o ? (p ? 254 : 0) : (4 * jg - 2 + 2 * p);
        const int cm = o ? (p ? 63 : 0) : (jg - 1);      // minus-corner col
        const float qwm = -1.0f + (2.0f * (float)cm + 1.0f) * (1.0f / 64.0f);

        // minus-corner colvec A, plus-corner colvec B (per dx):
        // p0: A = o?cv:qv, B = cv ;  p1: A = qv, B = o?qv:cv
        float A0[7], A1[7], B0[7], B1[7];
        #pragma unroll
        for (int b = 0; b < 7; ++b) {
            if (p == 0) {
                A0[b] = o ? cv0[b] : qv0[b];
                A1[b] = o ? cv1[b] : qv1[b];
                B0[b] = cv0[b];
                B1[b] = cv1[b];
            } else {
                A0[b] = qv0[b];
                A1[b] = qv1[b];
                B0[b] = o ? qv0[b] : cv0[b];
                B1[b] = o ? qv1[b] : cv1[b];
            }
        }
        #pragma unroll
        for (int sub = 0; sub < 2; ++sub) {
            const int j_e = jb + sub;
            const float cy = -1.0f + (2.0f * (float)j_e + 1.0f) * (1.0f / 256.0f);
            const float rel1m = (cy - qwm) * 64.0f;      // exact
            const float rel1p = rel1m + tm;              // exact

            float a00 = fabsf(rel0_0 * rel1m) + 1e-9f;
            float a01 = fabsf(rel0_0 * rel1p) + 1e-9f;
            float a10 = fabsf(rel0_1 * rel1m) + 1e-9f;
            float a11 = fabsf(rel0_1 * rel1p) + 1e-9f;
            float tot = ((a00 + a01) + a10) + a11;
            float rinv = __builtin_amdgcn_rcpf(tot);
            const float w00 = a11 * rinv, w01 = a10 * rinv;
            const float w10 = a01 * rinv, w11 = a00 * rinv;

            float ey0[7], ey1[7];
            embed7(sgy * rel1m, ey0);
            ey1[0] = 1.0f;
            ey1[1] = ym * ey0[1]; ey1[2] = ym * ey0[2];
            ey1[3] = ey0[3];      ey1[4] = ey0[4];
            ey1[5] = ym * ey0[5]; ey1[6] = ym * ey0[6];

            float v00 = 0.0f, v01 = 0.0f, v10 = 0.0f, v11 = 0.0f;
            #pragma unroll
            for (int b = 0; b < 7; ++b) {
                v00 = fmaf(A0[b], ey0[b], v00);
                v10 = fmaf(A1[b], ey0[b], v10);
                v01 = fmaf(B0[b], ey1[b], v01);
                v11 = fmaf(B1[b], ey1[b], v11);
            }
            float r = fmaf(v00, w00, fmaf(v01, w01, fmaf(v10, w10, v11 * w11)));
            if (p == 0) { if (sub == 0) acc_0 = r; else acc_1 = r; }
            else        { if (sub == 0) acc_2 = r; else acc_3 = r; }
        }
    }

    // ---- stores: two aligned float2 per thread ----
    const int i_out = fx ? (255 - i_e) : i_e;
    float* __restrict__ ob = out + (((size_t)n * 3 + k) * OHW + i_out) * OHW;
    const int jA = o ? 0   : (4 * jg - 2);
    const int jB = o ? 254 : (4 * jg);
    if (!fy) {
        *(float2*)&ob[jA] = make_float2(acc_0, acc_1);
        *(float2*)&ob[jB] = make_float2(acc_2, acc_3);
    } else {
        *(float2*)&ob[254 - jA] = make_float2(acc_1, acc_0);
        *(float2*)&ob[254 - jB] = make_float2(acc_3, acc_2);
    }
}

extern "C" void kernel_launch(void* const* d_in, const int* in_sizes, int n_in,
                              void* d_out, int out_size, void* d_ws, size_t ws_size,
                              hipStream_t stream) {
    const float* feat  = (const float*)d_in[0];
    const int*   flip1 = (const int*)d_in[3];
    const int*   flip3 = (const int*)d_in[4];
    float*       out   = (float*)d_out;

    dim3 grid(3, 64, 4);   // (k, i-group, n)
    dim3 block(256);
    hipLaunchKernelGGL(ope_render_kernel, grid, block, 0, stream,
                       feat, flip1, flip3, out);
}

// Round 11
// 10.254 us; speedup vs baseline: 1.6750x; 1.6750x over previous
//
#include <hip/hip_runtime.h>
#include <math.h>

// feat: (N=4, C3=147, H=64, W=64) fp32 ; out: (4, 3, 256, 256) fp32
// Exact structure (proved in fp32, verified R5-R10 passing):
//  - interior j-group q (lane jg=q>=1): iw- = q-1, iw+ = q for all 4 j's;
//    lane 0 (merged {0,1,254,255}): pair0 -> col 0 both, pair1 -> col 63 both.
//    Same structure on the i axis.
//  - rel_plus = rel_minus - 2 (interior) / rel_minus (boundary) exactly ->
//    embed(rel-2) = sign-flip of embed(rel) on components {1,2,5,6}.
// R11 = R8 + scalarization: row0 and the ex coefficients are wave-uniform but
// tid-derived; readfirstlane them into SGPRs so the 98-load stream uses a
// scalar base (saddr-form loads, 1 VALU or SALU per address instead of a
// 64-bit per-lane add chain) and the contraction FMAs read coefs from SGPRs.

#define FH 64
#define FW 64
#define FHW 4096          // FH*FW
#define NC3 147
#define OHW 256

__device__ __forceinline__ float rfl(float x) {
    return __int_as_float(__builtin_amdgcn_readfirstlane(__float_as_int(x)));
}

__device__ __forceinline__ void embed7(float r, float e[7]) {
    const float F1  = 1.5707963705062866f;  // float32(0.5*pi)
    const float SQ2 = 1.4142135381698608f;  // float32(sqrt(2))
    float a = r * F1;
    float s1 = __sinf(a), c1 = __cosf(a);
    float s2 = 2.0f * s1 * c1, c2 = c1 * c1 - s1 * s1;
    float s3 = s2 * c1 + c2 * s1, c3 = c2 * c1 - s2 * s1;
    e[0] = 1.0f;
    e[1] = SQ2 * c1; e[2] = SQ2 * s1;
    e[3] = SQ2 * c2; e[4] = SQ2 * s2;
    e[5] = SQ2 * c3; e[6] = SQ2 * s3;
}

// block = (k, ib, n); wave = i-member m; lane = j-group jg.
__global__ __launch_bounds__(256, 3) void ope_render_kernel(
    const float* __restrict__ feat,
    const int* __restrict__ pflip1,
    const int* __restrict__ pflip3,
    float* __restrict__ out)
{
    const int tid = threadIdx.x;
    const int k   = blockIdx.x;   // 0..2
    const int ib  = blockIdx.y;   // 0..63 (ib==0 merged {0,1,254,255})
    const int n   = blockIdx.z;   // 0..3
    const int flip1 = pflip1[0];
    const int flip3 = pflip3[0];

    const bool boundary = (ib == 0);
    const int rA = boundary ? 0  : (ib - 1);
    const int rB = boundary ? 63 : ib;

    const int m  = tid >> 6;      // wave id = i-member
    const int jg = tid & 63;      // lane = j-group (own column)
    const bool fx = (flip1 == 2) || (flip1 == 4);
    const bool fy = (flip1 == 1) || (flip1 == 4);
    const bool o  = (jg == 0);
    const float sgx = (flip3 == 2 || flip3 == 4) ? -1.0f : 1.0f;
    const float sgy = (flip3 == 1 || flip3 == 4) ? -1.0f : 1.0f;

    // x-axis: static rows; both corners' rel from one value
    const int i_e = boundary ? ((m < 2) ? m : 252 + m) : (4 * ib - 2 + m);
    const float cx = -1.0f + (2.0f * (float)i_e + 1.0f) * (1.0f / 256.0f);
    // row0 is wave-uniform (depends only on m) -> force into SGPR
    const int row0 = __builtin_amdgcn_readfirstlane(
        boundary ? ((m >> 1) ? rB : rA) : rA);
    const float qh0 = -1.0f + (2.0f * (float)row0 + 1.0f) * (1.0f / 64.0f);
    const float rel0_0 = (cx - qh0) * 64.0f;                  // exact
    const float rel0_1 = boundary ? rel0_0 : (rel0_0 - 2.0f); // exact

    float ex0[7], ex1[7];
    embed7(sgx * rel0_0, ex0);
    // wave-uniform coefficients -> SGPRs (frees VGPRs; fma reads 1 sgpr)
    #pragma unroll
    for (int b = 0; b < 7; ++b) ex0[b] = rfl(ex0[b]);
    {   // embed(r -/+ 2) = sign-flip on {1,2,5,6}; boundary: identical
        const float xm = boundary ? 1.0f : -1.0f;
        ex1[0] = 1.0f;
        ex1[1] = xm * ex0[1]; ex1[2] = xm * ex0[2];
        ex1[3] = ex0[3];      ex1[4] = ex0[4];
        ex1[5] = xm * ex0[5]; ex1[6] = xm * ex0[6];
    }

    // ---- direct-global streamed contraction (no LDS, no barrier) ----
    // scalar (SGPR) base: n, k block-uniform; row0 readfirstlane'd.
    // lane offset = jg (column) -> saddr-form coalesced 256B loads.
    const float* __restrict__ b0 =
        feat + (((size_t)n * NC3 + k * 49) * FH + row0) * FW;
    float cv0[7], cv1[7];
    #pragma unroll
    for (int b = 0; b < 7; ++b) { cv0[b] = 0.0f; cv1[b] = 0.0f; }
    if (!boundary) {
        const float* __restrict__ b1 = b0 + (rB - rA) * FW;   // row rB, same ch
        #pragma unroll
        for (int c = 0; c < 49; ++c) {
            cv0[c % 7] = fmaf(ex0[c / 7], b0[c * FHW + jg], cv0[c % 7]);
            cv1[c % 7] = fmaf(ex1[c / 7], b1[c * FHW + jg], cv1[c % 7]);
        }
    } else {
        #pragma unroll
        for (int c = 0; c < 49; ++c)
            cv0[c % 7] = fmaf(ex0[c / 7], b0[c * FHW + jg], cv0[c % 7]);
        #pragma unroll
        for (int b = 0; b < 7; ++b) cv1[b] = cv0[b];   // same row, ex1==ex0
    }

    // ---- neighbor column via intra-wave shuffle (lane jg-1; lane0 <- 63) ----
    const int srcl = (jg + 63) & 63;
    float qv0[7], qv1[7];
    #pragma unroll
    for (int b = 0; b < 7; ++b) {
        qv0[b] = __shfl(cv0[b], srcl, 64);
        qv1[b] = __shfl(cv1[b], srcl, 64);
    }

    // ---- per-pair inline y-math + dots (verified R5-R10) ----
    const float tm = o ? 0.0f : -2.0f;   // rel1_plus = rel1_minus + tm
    const float ym = o ? 1.0f : -1.0f;   // ey1 sign multiplier
    float acc0, acc1, acc2, acc3;
    #pragma unroll
    for (int p = 0; p < 2; ++p) {
        const int jb = o ? (p ? 254 : 0) : (4 * jg - 2 + 2 * p);
        const int cm = o ? (p ? 63 : 0) : (jg - 1);      // minus-corner col
        const float qwm = -1.0f + (2.0f * (float)cm + 1.0f) * (1.0f / 64.0f);

        // minus-corner colvec A, plus-corner colvec B (per dx):
        // p0: A = o?cv:qv, B = cv ;  p1: A = qv, B = o?qv:cv
        float A0[7], A1[7], B0[7], B1[7];
        #pragma unroll
        for (int b = 0; b < 7; ++b) {
            if (p == 0) {
                A0[b] = o ? cv0[b] : qv0[b];
                A1[b] = o ? cv1[b] : qv1[b];
                B0[b] = cv0[b];
                B1[b] = cv1[b];
            } else {
                A0[b] = qv0[b];
                A1[b] = qv1[b];
                B0[b] = o ? qv0[b] : cv0[b];
                B1[b] = o ? qv1[b] : cv1[b];
            }
        }
        #pragma unroll
        for (int sub = 0; sub < 2; ++sub) {
            const int j_e = jb + sub;
            const float cy = -1.0f + (2.0f * (float)j_e + 1.0f) * (1.0f / 256.0f);
            const float rel1m = (cy - qwm) * 64.0f;      // exact
            const float rel1p = rel1m + tm;              // exact

            float a00 = fabsf(rel0_0 * rel1m) + 1e-9f;
            float a01 = fabsf(rel0_0 * rel1p) + 1e-9f;
            float a10 = fabsf(rel0_1 * rel1m) + 1e-9f;
            float a11 = fabsf(rel0_1 * rel1p) + 1e-9f;
            float tot = ((a00 + a01) + a10) + a11;
            float rinv = __builtin_amdgcn_rcpf(tot);
            const float w00 = a11 * rinv, w01 = a10 * rinv;
            const float w10 = a01 * rinv, w11 = a00 * rinv;

            float ey0[7], ey1[7];
            embed7(sgy * rel1m, ey0);
            ey1[0] = 1.0f;
            ey1[1] = ym * ey0[1]; ey1[2] = ym * ey0[2];
            ey1[3] = ey0[3];      ey1[4] = ey0[4];
            ey1[5] = ym * ey0[5]; ey1[6] = ym * ey0[6];

            float v00 = 0.0f, v01 = 0.0f, v10 = 0.0f, v11 = 0.0f;
            #pragma unroll
            for (int b = 0; b < 7; ++b) {
                v00 = fmaf(A0[b], ey0[b], v00);
                v10 = fmaf(A1[b], ey0[b], v10);
                v01 = fmaf(B0[b], ey1[b], v01);
                v11 = fmaf(B1[b], ey1[b], v11);
            }
            float r = fmaf(v00, w00, fmaf(v01, w01, fmaf(v10, w10, v11 * w11)));
            if (p == 0) { if (sub == 0) acc0 = r; else acc1 = r; }
            else        { if (sub == 0) acc2 = r; else acc3 = r; }
        }
    }

    // ---- stores: two aligned float2 per thread ----
    const int i_out = fx ? (255 - i_e) : i_e;
    float* __restrict__ ob = out + (((size_t)n * 3 + k) * OHW + i_out) * OHW;
    const int jA = o ? 0   : (4 * jg - 2);
    const int jB = o ? 254 : (4 * jg);
    if (!fy) {
        *(float2*)&ob[jA] = make_float2(acc0, acc1);
        *(float2*)&ob[jB] = make_float2(acc2, acc3);
    } else {
        *(float2*)&ob[254 - jA] = make_float2(acc1, acc0);
        *(float2*)&ob[254 - jB] = make_float2(acc3, acc2);
    }
}

extern "C" void kernel_launch(void* const* d_in, const int* in_sizes, int n_in,
                              void* d_out, int out_size, void* d_ws, size_t ws_size,
                              hipStream_t stream) {
    const float* feat  = (const float*)d_in[0];
    const int*   flip1 = (const int*)d_in[3];
    const int*   flip3 = (const int*)d_in[4];
    float*       out   = (float*)d_out;

    dim3 grid(3, 64, 4);   // (k, i-group, n)
    dim3 block(256);
    hipLaunchKernelGGL(ope_render_kernel, grid, block, 0, stream,
                       feat, flip1, flip3, out);
}